// Round 4
// baseline (473.589 us; speedup 1.0000x reference)
//
#include <hip/hip_runtime.h>

typedef _Float16 f16;
typedef _Float16 f16x8 __attribute__((ext_vector_type(8)));
typedef float f32x4 __attribute__((ext_vector_type(4)));
typedef uint32_t u32x4 __attribute__((ext_vector_type(4)));

#define NBLK 8
#define MFMA(a, b, c) __builtin_amdgcn_mfma_f32_16x16x32_f16(a, b, c, 0, 0, 0)

// Consumer-side K position k -> producer-side slot feature index.
__device__ __forceinline__ int pinv(int k) {
  return 16 * (2 * (k >> 5) + ((k >> 2) & 1)) + 4 * ((k >> 3) & 3) + (k & 3);
}
__device__ __forceinline__ float hi_part(float v) { return (float)(f16)v; }
__device__ __forceinline__ float lo_part(float v) { f16 h = (f16)v; return v - (float)h; }

// v_exp_f32 computes 2^x; gfx9 has full VALU interlocks (no manual nops).
__device__ __forceinline__ float fast_exp2(float x) {
  float r; asm("v_exp_f32 %0, %1" : "=v"(r) : "v"(x)); return r;
}
__device__ __forceinline__ float fast_rcp(float x) {
  float r; asm("v_rcp_f32 %0, %1" : "=v"(r) : "v"(x)); return r;
}
__device__ __forceinline__ uint32_t pkrtz_u(float a, float b) {
  auto p = __builtin_amdgcn_cvt_pkrtz(a, b);  // __fp16x2 -> reinterpret as dword
  return __builtin_bit_cast(uint32_t, p);
}
// Exact hi/lo split: hi keeps top 10 mantissa bits (exactly f16-representable).
__device__ __forceinline__ float hi_mask(float v) {
  uint32_t u = __builtin_bit_cast(uint32_t, v) & 0xFFFFE000u;
  return __builtin_bit_cast(float, u);
}

// One-time weight prep: writes fragment-layout f16 images to ws.
// Per block i: img 0..3   A1[t]   (K: 0-3 W1hi, 4-7 W1lo, 8-11 W1hi, 12/13 b1 hi/lo)
//              img 4..11  A2hi[t*2+s], img 12..19 A2lo[t*2+s]
//              img 20,21  A3hi[s],     img 22,23  A3lo[s]
__global__ void prep_weights(const float* __restrict__ W1, const float* __restrict__ b1,
                             const float* __restrict__ W2, const float* __restrict__ W3,
                             f16* __restrict__ wsp) {
  int i = blockIdx.x / 24;
  int img = blockIdx.x % 24;
  int lane = threadIdx.x;
  int c = lane & 15, g = lane >> 4;
  f16 vals[8];
#pragma unroll
  for (int e = 0; e < 8; ++e) {
    float out = 0.f;
    if (img < 4) {
      int t = img, m = 16 * t + c, k = 8 * g + e;
      if (k < 4)        out = hi_part(W1[i * 256 + m * 4 + k]);
      else if (k < 8)   out = lo_part(W1[i * 256 + m * 4 + (k - 4)]);
      else if (k < 12)  out = hi_part(W1[i * 256 + m * 4 + (k - 8)]);
      else if (k == 12) out = hi_part(b1[i * 64 + m]);
      else if (k == 13) out = lo_part(b1[i * 64 + m]);
      else out = 0.f;
    } else if (img < 20) {
      bool isLo = (img >= 12);
      int q = isLo ? (img - 12) : (img - 4);
      int t = q >> 1, s = q & 1, m = 16 * t + c;
      int k = 32 * s + 8 * g + e;
      float v = W2[i * 4096 + m * 64 + pinv(k)];
      out = isLo ? lo_part(v) : hi_part(v);
    } else {
      bool isLo = (img >= 22);
      int s = isLo ? (img - 22) : (img - 20);
      int k = 32 * s + 8 * g + e;
      float v = (c < 4) ? W3[i * 256 + c * 64 + pinv(k)] : 0.f;
      out = isLo ? lo_part(v) : hi_part(v);
    }
    vals[e] = (f16)out;
  }
  f16x8 vv = {vals[0], vals[1], vals[2], vals[3], vals[4], vals[5], vals[6], vals[7]};
  *(f16x8*)(wsp + ((size_t)i * 24 + img) * 512 + (size_t)lane * 8) = vv;
}

// D (4 tiles of f32x4) -> relu -> exact-split f16 hi/lo fragments via pkrtz.
__device__ __forceinline__ void make_b(const f32x4 d[4], f16x8 bh[2], f16x8 bl[2]) {
#pragma unroll
  for (int s = 0; s < 2; ++s) {
    float r[8], hf[8], lf[8];
#pragma unroll
    for (int e = 0; e < 4; ++e) {
      r[e]     = fmaxf(d[2 * s][e], 0.f);
      r[4 + e] = fmaxf(d[2 * s + 1][e], 0.f);
    }
#pragma unroll
    for (int e = 0; e < 8; ++e) {
      hf[e] = hi_mask(r[e]);     // exact in f16
      lf[e] = r[e] - hf[e];      // exact residual
    }
    u32x4 uh = {pkrtz_u(hf[0], hf[1]), pkrtz_u(hf[2], hf[3]),
                pkrtz_u(hf[4], hf[5]), pkrtz_u(hf[6], hf[7])};
    u32x4 ul = {pkrtz_u(lf[0], lf[1]), pkrtz_u(lf[2], lf[3]),
                pkrtz_u(lf[4], lf[5]), pkrtz_u(lf[6], lf[7])};
    bh[s] = __builtin_bit_cast(f16x8, uh);
    bl[s] = __builtin_bit_cast(f16x8, ul);
  }
}

__global__ __launch_bounds__(256) void cinn_mfma_kernel(
    const float* __restrict__ q_feat, const float* __restrict__ Hc,
    const float* __restrict__ b2, const float* __restrict__ b3,
    const float* __restrict__ w_perm, const float* __restrict__ g_scale,
    const float* __restrict__ g_offset, const f16* __restrict__ wf,
    float* __restrict__ out_x, float* __restrict__ out_ld, int n) {
  __shared__ alignas(16) float s_scale[NBLK][4];
  __shared__ float s_logsum_tot;
  if (threadIdx.x < NBLK) {
    int i = threadIdx.x;
    float ls = 0.f;
    for (int d = 0; d < 4; ++d) {
      float gs = g_scale[i * 4 + d];
      float sc = 0.2f * log1pf(expf(0.5f * gs));
      s_scale[i][d] = sc;
      ls += logf(sc);
    }
    // sum of all 8 blocks' log-scale sums, computed redundantly-free via atomic-free trick:
    // each thread writes partial; thread 0 sums after barrier (done below).
    s_scale[i][0] = s_scale[i][0];  // keep
    __shared__ float s_part[NBLK];
    s_part[i] = ls;
    __syncthreads();
    if (i == 0) {
      float t = 0.f;
      for (int k = 0; k < NBLK; ++k) t += s_part[k];
      s_logsum_tot = t;
    }
  } else {
    __syncthreads();
  }
  __syncthreads();

  int lane = threadIdx.x & 63;
  int c = lane & 15, g = lane >> 4;
  bool g0 = (g == 0), g1 = (g == 1);
  int wave = (blockIdx.x * blockDim.x + threadIdx.x) >> 6;
  int pt = wave * 16 + c;
  if (pt >= n) pt = n - 1;  // no early return: MFMA needs all 64 lanes

  float4 xv = *reinterpret_cast<const float4*>(q_feat + (size_t)pt * 4);
  float x0 = xv.x, x1 = xv.y, x2 = xv.z, x3 = xv.w;
  float2 hv = *reinterpret_cast<const float2*>(Hc + (size_t)pt * 2);
  float logdet = 0.f;

  // Loop-invariant conditioner hi/lo packs
  float chf0 = hi_mask(hv.x), chf1 = hi_mask(hv.y);
  uint32_t ch_pk = pkrtz_u(chf0, chf1);
  uint32_t cl_pk = pkrtz_u(hv.x - chf0, hv.y - chf1);
  const uint32_t ones_pk = 0x3C003C00u;  // packed f16 {1,1}
  const f32x4 zero4 = {0.f, 0.f, 0.f, 0.f};
  const float LOG2E = 1.4426950408889634f;

#pragma unroll 1
  for (int i = 0; i < NBLK; ++i) {
    const f16* wb = wf + (size_t)i * 24 * 512 + (size_t)lane * 8;
    // B1 (k = 8g+e): g=0 -> {xh,ch,xh,ch}; g=1 -> {xl,cl,1,0}; g>=2 -> 0
    float xhf0 = hi_mask(x0), xhf1 = hi_mask(x1);
    uint32_t xh_pk = pkrtz_u(xhf0, xhf1);
    uint32_t xl_pk = pkrtz_u(x0 - xhf0, x1 - xhf1);
    u32x4 B1u = {g0 ? xh_pk : (g1 ? xl_pk : 0u),
                 g0 ? ch_pk : (g1 ? cl_pk : 0u),
                 g0 ? xh_pk : (g1 ? ones_pk : 0u),
                 g0 ? ch_pk : 0u};
    f16x8 B1 = __builtin_bit_cast(f16x8, B1u);

    // L1 (split terms + bias folded into K-slots)
    f32x4 d1[4];
#pragma unroll
    for (int t = 0; t < 4; ++t) {
      f16x8 a = *(const f16x8*)(wb + t * 512);
      d1[t] = MFMA(a, B1, zero4);
    }
    f16x8 b2h[2], b2l[2];
    make_b(d1, b2h, b2l);

    // L2: hi*hi + lo*hi + hi*lo
    f32x4 d2[4];
#pragma unroll
    for (int t = 0; t < 4; ++t) {
      f32x4 acc = zero4;
#pragma unroll
      for (int s = 0; s < 2; ++s) {
        f16x8 ah = *(const f16x8*)(wb + (4 + 2 * t + s) * 512);
        f16x8 al = *(const f16x8*)(wb + (12 + 2 * t + s) * 512);
        acc = MFMA(ah, b2h[s], acc);
        acc = MFMA(al, b2h[s], acc);
        acc = MFMA(ah, b2l[s], acc);
      }
      const float4 bv = *reinterpret_cast<const float4*>(b2 + i * 64 + 16 * t + 4 * g);
      acc[0] += bv.x; acc[1] += bv.y; acc[2] += bv.z; acc[3] += bv.w;
      d2[t] = acc;
    }
    f16x8 b3h[2], b3l[2];
    make_b(d2, b3h, b3l);

    // L3
    f32x4 d3 = zero4;
#pragma unroll
    for (int s = 0; s < 2; ++s) {
      f16x8 ah = *(const f16x8*)(wb + (20 + s) * 512);
      f16x8 al = *(const f16x8*)(wb + (22 + s) * 512);
      d3 = MFMA(ah, b3h[s], d3);
      d3 = MFMA(al, b3h[s], d3);
      d3 = MFMA(ah, b3l[s], d3);
    }

    // a-values live on g=0 lanes; broadcast so every lane keeps true x-state.
    float a0  = (__shfl(d3[0], c, 64) + b3[i * 4 + 0]) * 0.1f;
    float a1  = (__shfl(d3[1], c, 64) + b3[i * 4 + 1]) * 0.1f;
    float a2v = (__shfl(d3[2], c, 64) + b3[i * 4 + 2]) * 0.1f;
    float a3v = (__shfl(d3[3], c, 64) + b3[i * 4 + 3]) * 0.1f;
    // s = 2*tanh(a) = 2 - 4/(e^{2a}+1); exp via native 2^x
    float u0 = fast_exp2(a0 * (2.f * LOG2E));
    float u1 = fast_exp2(a1 * (2.f * LOG2E));
    float s0 = fmaf(-4.f, fast_rcp(u0 + 1.f), 2.f);
    float s1 = fmaf(-4.f, fast_rcp(u1 + 1.f), 2.f);
    float e0 = fast_exp2(s0 * LOG2E);
    float e1 = fast_exp2(s1 * LOG2E);
    x2 = fmaf(x2, e0, a2v);
    x3 = fmaf(x3, e1, a3v);
    logdet += s0 + s1;

    // actnorm + permutation (exact f32)
    float y0 = fmaf(x0, s_scale[i][0], g_offset[i * 4 + 0]);
    float y1 = fmaf(x1, s_scale[i][1], g_offset[i * 4 + 1]);
    float y2 = fmaf(x2, s_scale[i][2], g_offset[i * 4 + 2]);
    float y3 = fmaf(x3, s_scale[i][3], g_offset[i * 4 + 3]);
    const float* wp = w_perm + i * 16;
    float nx0 = wp[0] * y0 + wp[1] * y1 + wp[2] * y2 + wp[3] * y3;
    float nx1 = wp[4] * y0 + wp[5] * y1 + wp[6] * y2 + wp[7] * y3;
    float nx2 = wp[8] * y0 + wp[9] * y1 + wp[10] * y2 + wp[11] * y3;
    float nx3 = wp[12] * y0 + wp[13] * y1 + wp[14] * y2 + wp[15] * y3;
    x0 = nx0; x1 = nx1; x2 = nx2; x3 = nx3;
  }
  logdet += s_logsum_tot;

  if (lane < 16) {
    *reinterpret_cast<float4*>(out_x + (size_t)pt * 4) = make_float4(x0, x1, x2, x3);
    out_ld[pt] = logdet;
  }
}

extern "C" void kernel_launch(void* const* d_in, const int* in_sizes, int n_in,
                              void* d_out, int out_size, void* d_ws, size_t ws_size,
                              hipStream_t stream) {
  const float* q_feat   = (const float*)d_in[0];
  const float* Hc       = (const float*)d_in[1];
  const float* W1       = (const float*)d_in[2];
  const float* b1       = (const float*)d_in[3];
  const float* W2       = (const float*)d_in[4];
  const float* b2       = (const float*)d_in[5];
  const float* W3       = (const float*)d_in[6];
  const float* b3       = (const float*)d_in[7];
  const float* w_perm   = (const float*)d_in[8];
  const float* g_scale  = (const float*)d_in[9];
  const float* g_offset = (const float*)d_in[10];

  int n = in_sizes[0] / 4;
  float* out_x  = (float*)d_out;
  float* out_ld = out_x + (size_t)n * 4;
  f16* wf = (f16*)d_ws;  // 8*24*512*2 = 196608 bytes

  hipLaunchKernelGGL(prep_weights, dim3(NBLK * 24), dim3(64), 0, stream,
                     W1, b1, W2, W3, wf);
  int blocks = (n + 63) / 64;  // 64 points per 256-thread block (16/wave)
  hipLaunchKernelGGL(cinn_mfma_kernel, dim3(blocks), dim3(256), 0, stream,
                     q_feat, Hc, b2, b3, w_perm, g_scale, g_offset, wf,
                     out_x, out_ld, n);
}

// Round 5
// 329.670 us; speedup vs baseline: 1.4366x; 1.4366x over previous
//
#include <hip/hip_runtime.h>

typedef _Float16 f16;
typedef _Float16 f16x8 __attribute__((ext_vector_type(8)));
typedef float f32x4 __attribute__((ext_vector_type(4)));
typedef uint32_t u32x4 __attribute__((ext_vector_type(4)));

#define NBLK 8
#define MFMA(a, b, c) __builtin_amdgcn_mfma_f32_16x16x32_f16(a, b, c, 0, 0, 0)

// Consumer-side K position k -> producer-side slot feature index.
__device__ __forceinline__ int pinv(int k) {
  return 16 * (2 * (k >> 5) + ((k >> 2) & 1)) + 4 * ((k >> 3) & 3) + (k & 3);
}
__device__ __forceinline__ float hi_part(float v) { return (float)(f16)v; }
__device__ __forceinline__ float lo_part(float v) { f16 h = (f16)v; return v - (float)h; }

__device__ __forceinline__ float fast_exp2(float x) {
  float r; asm("v_exp_f32 %0, %1" : "=v"(r) : "v"(x)); return r;
}
__device__ __forceinline__ float fast_rcp(float x) {
  float r; asm("v_rcp_f32 %0, %1" : "=v"(r) : "v"(x)); return r;
}
__device__ __forceinline__ uint32_t pkrtz_u(float a, float b) {
  auto p = __builtin_amdgcn_cvt_pkrtz(a, b);
  return __builtin_bit_cast(uint32_t, p);
}
// Exact hi/lo split: hi keeps top 10 mantissa bits (exactly f16-representable).
__device__ __forceinline__ float hi_mask(float v) {
  uint32_t u = __builtin_bit_cast(uint32_t, v) & 0xFFFFE000u;
  return __builtin_bit_cast(float, u);
}

// One-time weight prep (unchanged layout):
// Per block i: img 0..3   A1[t]   (K: 0-3 W1hi, 4-7 W1lo, 8-11 W1hi, 12/13 b1 hi/lo)
//              img 4..11  A2hi[t*2+s], img 12..19 A2lo[t*2+s]
//              img 20,21  A3hi[s],     img 22,23  A3lo[s]
__global__ void prep_weights(const float* __restrict__ W1, const float* __restrict__ b1,
                             const float* __restrict__ W2, const float* __restrict__ W3,
                             f16* __restrict__ wsp) {
  int i = blockIdx.x / 24;
  int img = blockIdx.x % 24;
  int lane = threadIdx.x;
  int c = lane & 15, g = lane >> 4;
  f16 vals[8];
#pragma unroll
  for (int e = 0; e < 8; ++e) {
    float out = 0.f;
    if (img < 4) {
      int t = img, m = 16 * t + c, k = 8 * g + e;
      if (k < 4)        out = hi_part(W1[i * 256 + m * 4 + k]);
      else if (k < 8)   out = lo_part(W1[i * 256 + m * 4 + (k - 4)]);
      else if (k < 12)  out = hi_part(W1[i * 256 + m * 4 + (k - 8)]);
      else if (k == 12) out = hi_part(b1[i * 64 + m]);
      else if (k == 13) out = lo_part(b1[i * 64 + m]);
      else out = 0.f;
    } else if (img < 20) {
      bool isLo = (img >= 12);
      int q = isLo ? (img - 12) : (img - 4);
      int t = q >> 1, s = q & 1, m = 16 * t + c;
      int k = 32 * s + 8 * g + e;
      float v = W2[i * 4096 + m * 64 + pinv(k)];
      out = isLo ? lo_part(v) : hi_part(v);
    } else {
      bool isLo = (img >= 22);
      int s = isLo ? (img - 22) : (img - 20);
      int k = 32 * s + 8 * g + e;
      float v = (c < 4) ? W3[i * 256 + c * 64 + pinv(k)] : 0.f;
      out = isLo ? lo_part(v) : hi_part(v);
    }
    vals[e] = (f16)out;
  }
  f16x8 vv = {vals[0], vals[1], vals[2], vals[3], vals[4], vals[5], vals[6], vals[7]};
  *(f16x8*)(wsp + ((size_t)i * 24 + img) * 512 + (size_t)lane * 8) = vv;
}

// D (4 tiles of f32x4) -> relu -> exact-split f16 hi/lo fragments via pkrtz.
__device__ __forceinline__ void make_b(const f32x4 d[4], f16x8 bh[2], f16x8 bl[2]) {
#pragma unroll
  for (int s = 0; s < 2; ++s) {
    float r[8], hf[8], lf[8];
#pragma unroll
    for (int e = 0; e < 4; ++e) {
      r[e]     = fmaxf(d[2 * s][e], 0.f);
      r[4 + e] = fmaxf(d[2 * s + 1][e], 0.f);
    }
#pragma unroll
    for (int e = 0; e < 8; ++e) {
      hf[e] = hi_mask(r[e]);
      lf[e] = r[e] - hf[e];
    }
    u32x4 uh = {pkrtz_u(hf[0], hf[1]), pkrtz_u(hf[2], hf[3]),
                pkrtz_u(hf[4], hf[5]), pkrtz_u(hf[6], hf[7])};
    u32x4 ul = {pkrtz_u(lf[0], lf[1]), pkrtz_u(lf[2], lf[3]),
                pkrtz_u(lf[4], lf[5]), pkrtz_u(lf[6], lf[7])};
    bh[s] = __builtin_bit_cast(f16x8, uh);
    bl[s] = __builtin_bit_cast(f16x8, ul);
  }
}

struct Pt {
  float x0, x1, x2, x3, ld;
  uint32_t ch_pk, cl_pk;
};

__device__ __forceinline__ f16x8 build_B1(const Pt& s, bool g0, bool g1) {
  const uint32_t ones_pk = 0x3C003C00u;  // packed f16 {1,1}
  float xh0 = hi_mask(s.x0), xh1 = hi_mask(s.x1);
  uint32_t xh_pk = pkrtz_u(xh0, xh1);
  uint32_t xl_pk = pkrtz_u(s.x0 - xh0, s.x1 - xh1);
  u32x4 B1u = {g0 ? xh_pk : (g1 ? xl_pk : 0u),
               g0 ? s.ch_pk : (g1 ? s.cl_pk : 0u),
               g0 ? xh_pk : (g1 ? ones_pk : 0u),
               g0 ? s.ch_pk : 0u};
  return __builtin_bit_cast(f16x8, B1u);
}

__device__ __forceinline__ void couple(Pt& st, const f32x4 d3, int c, int i,
                                       const float* __restrict__ b3,
                                       const float* __restrict__ w_perm,
                                       const float* __restrict__ g_offset,
                                       const float sc0, const float sc1,
                                       const float sc2, const float sc3) {
  const float LOG2E = 1.4426950408889634f;
  float a0  = (__shfl(d3[0], c, 64) + b3[i * 4 + 0]) * 0.1f;
  float a1  = (__shfl(d3[1], c, 64) + b3[i * 4 + 1]) * 0.1f;
  float a2v = (__shfl(d3[2], c, 64) + b3[i * 4 + 2]) * 0.1f;
  float a3v = (__shfl(d3[3], c, 64) + b3[i * 4 + 3]) * 0.1f;
  // s = 2*tanh(a) = 2 - 4/(e^{2a}+1)
  float u0 = fast_exp2(a0 * (2.f * LOG2E));
  float u1 = fast_exp2(a1 * (2.f * LOG2E));
  float s0 = fmaf(-4.f, fast_rcp(u0 + 1.f), 2.f);
  float s1 = fmaf(-4.f, fast_rcp(u1 + 1.f), 2.f);
  float e0 = fast_exp2(s0 * LOG2E);
  float e1 = fast_exp2(s1 * LOG2E);
  st.x2 = fmaf(st.x2, e0, a2v);
  st.x3 = fmaf(st.x3, e1, a3v);
  st.ld += s0 + s1;
  float y0 = fmaf(st.x0, sc0, g_offset[i * 4 + 0]);
  float y1 = fmaf(st.x1, sc1, g_offset[i * 4 + 1]);
  float y2 = fmaf(st.x2, sc2, g_offset[i * 4 + 2]);
  float y3 = fmaf(st.x3, sc3, g_offset[i * 4 + 3]);
  const float* wp = w_perm + i * 16;
  float nx0 = wp[0] * y0 + wp[1] * y1 + wp[2] * y2 + wp[3] * y3;
  float nx1 = wp[4] * y0 + wp[5] * y1 + wp[6] * y2 + wp[7] * y3;
  float nx2 = wp[8] * y0 + wp[9] * y1 + wp[10] * y2 + wp[11] * y3;
  float nx3 = wp[12] * y0 + wp[13] * y1 + wp[14] * y2 + wp[15] * y3;
  st.x0 = nx0; st.x1 = nx1; st.x2 = nx2; st.x3 = nx3;
}

// Dual-stream: each wave handles 32 points (two independent 16-point streams).
// Weight fragments are loaded once and feed both streams' MFMAs; each stream's
// serial shfl/exp chain hides under the other's compute.
__global__ __launch_bounds__(256) void cinn_mfma_kernel(
    const float* __restrict__ q_feat, const float* __restrict__ Hc,
    const float* __restrict__ b2, const float* __restrict__ b3,
    const float* __restrict__ w_perm, const float* __restrict__ g_scale,
    const float* __restrict__ g_offset, const f16* __restrict__ wf,
    float* __restrict__ out_x, float* __restrict__ out_ld, int n) {
  __shared__ alignas(16) float s_scale[NBLK][4];
  __shared__ float s_part[NBLK];
  __shared__ float s_logsum_tot;
  if (threadIdx.x < NBLK) {
    int i = threadIdx.x;
    float ls = 0.f;
    for (int d = 0; d < 4; ++d) {
      float gs = g_scale[i * 4 + d];
      float sc = 0.2f * log1pf(expf(0.5f * gs));
      s_scale[i][d] = sc;
      ls += logf(sc);
    }
    s_part[i] = ls;
  }
  __syncthreads();
  if (threadIdx.x == 0) {
    float t = 0.f;
    for (int k = 0; k < NBLK; ++k) t += s_part[k];
    s_logsum_tot = t;
  }
  __syncthreads();

  int lane = threadIdx.x & 63;
  int c = lane & 15, g = lane >> 4;
  bool g0 = (g == 0), g1 = (g == 1);
  int wave = (blockIdx.x * blockDim.x + threadIdx.x) >> 6;
  int pa = wave * 32 + c;
  int pb = pa + 16;
  if (pa >= n) pa = n - 1;
  if (pb >= n) pb = n - 1;

  Pt A, B;
  {
    float4 xv = *reinterpret_cast<const float4*>(q_feat + (size_t)pa * 4);
    A.x0 = xv.x; A.x1 = xv.y; A.x2 = xv.z; A.x3 = xv.w; A.ld = 0.f;
    float2 hv = *reinterpret_cast<const float2*>(Hc + (size_t)pa * 2);
    float h0 = hi_mask(hv.x), h1 = hi_mask(hv.y);
    A.ch_pk = pkrtz_u(h0, h1);
    A.cl_pk = pkrtz_u(hv.x - h0, hv.y - h1);
  }
  {
    float4 xv = *reinterpret_cast<const float4*>(q_feat + (size_t)pb * 4);
    B.x0 = xv.x; B.x1 = xv.y; B.x2 = xv.z; B.x3 = xv.w; B.ld = 0.f;
    float2 hv = *reinterpret_cast<const float2*>(Hc + (size_t)pb * 2);
    float h0 = hi_mask(hv.x), h1 = hi_mask(hv.y);
    B.ch_pk = pkrtz_u(h0, h1);
    B.cl_pk = pkrtz_u(hv.x - h0, hv.y - h1);
  }

  const f32x4 zero4 = {0.f, 0.f, 0.f, 0.f};

#pragma unroll 1
  for (int i = 0; i < NBLK; ++i) {
    const f16* wb = wf + (size_t)i * 24 * 512 + (size_t)lane * 8;
    f16x8 B1a = build_B1(A, g0, g1);
    f16x8 B1b = build_B1(B, g0, g1);

    // L1
    f32x4 d1a[4], d1b[4];
#pragma unroll
    for (int t = 0; t < 4; ++t) {
      f16x8 a = *(const f16x8*)(wb + t * 512);
      d1a[t] = MFMA(a, B1a, zero4);
      d1b[t] = MFMA(a, B1b, zero4);
    }
    f16x8 b2ha[2], b2la[2], b2hb[2], b2lb[2];
    make_b(d1a, b2ha, b2la);
    make_b(d1b, b2hb, b2lb);

    // L2: hi*hi + lo*hi + hi*lo (A-fragments shared between streams)
    f32x4 d2a[4], d2b[4];
#pragma unroll
    for (int t = 0; t < 4; ++t) {
      f32x4 aa = zero4, ab = zero4;
#pragma unroll
      for (int s = 0; s < 2; ++s) {
        f16x8 ah = *(const f16x8*)(wb + (4 + 2 * t + s) * 512);
        f16x8 al = *(const f16x8*)(wb + (12 + 2 * t + s) * 512);
        aa = MFMA(ah, b2ha[s], aa);
        ab = MFMA(ah, b2hb[s], ab);
        aa = MFMA(al, b2ha[s], aa);
        ab = MFMA(al, b2hb[s], ab);
        aa = MFMA(ah, b2la[s], aa);
        ab = MFMA(ah, b2lb[s], ab);
      }
      const float4 bv = *reinterpret_cast<const float4*>(b2 + i * 64 + 16 * t + 4 * g);
      aa[0] += bv.x; aa[1] += bv.y; aa[2] += bv.z; aa[3] += bv.w;
      ab[0] += bv.x; ab[1] += bv.y; ab[2] += bv.z; ab[3] += bv.w;
      d2a[t] = aa; d2b[t] = ab;
    }
    f16x8 b3ha[2], b3la[2], b3hb[2], b3lb[2];
    make_b(d2a, b3ha, b3la);
    make_b(d2b, b3hb, b3lb);

    // L3
    f32x4 d3a = zero4, d3b = zero4;
#pragma unroll
    for (int s = 0; s < 2; ++s) {
      f16x8 ah = *(const f16x8*)(wb + (20 + s) * 512);
      f16x8 al = *(const f16x8*)(wb + (22 + s) * 512);
      d3a = MFMA(ah, b3ha[s], d3a);
      d3b = MFMA(ah, b3hb[s], d3b);
      d3a = MFMA(al, b3ha[s], d3a);
      d3b = MFMA(al, b3hb[s], d3b);
      d3a = MFMA(ah, b3la[s], d3a);
      d3b = MFMA(ah, b3lb[s], d3b);
    }

    float sc0 = s_scale[i][0], sc1 = s_scale[i][1];
    float sc2 = s_scale[i][2], sc3 = s_scale[i][3];
    couple(A, d3a, c, i, b3, w_perm, g_offset, sc0, sc1, sc2, sc3);
    couple(B, d3b, c, i, b3, w_perm, g_offset, sc0, sc1, sc2, sc3);
  }

  if (lane < 16) {
    *reinterpret_cast<float4*>(out_x + (size_t)pa * 4) =
        make_float4(A.x0, A.x1, A.x2, A.x3);
    out_ld[pa] = A.ld + s_logsum_tot;
    *reinterpret_cast<float4*>(out_x + (size_t)pb * 4) =
        make_float4(B.x0, B.x1, B.x2, B.x3);
    out_ld[pb] = B.ld + s_logsum_tot;
  }
}

extern "C" void kernel_launch(void* const* d_in, const int* in_sizes, int n_in,
                              void* d_out, int out_size, void* d_ws, size_t ws_size,
                              hipStream_t stream) {
  const float* q_feat   = (const float*)d_in[0];
  const float* Hc       = (const float*)d_in[1];
  const float* W1       = (const float*)d_in[2];
  const float* b1       = (const float*)d_in[3];
  const float* W2       = (const float*)d_in[4];
  const float* b2       = (const float*)d_in[5];
  const float* W3       = (const float*)d_in[6];
  const float* b3       = (const float*)d_in[7];
  const float* w_perm   = (const float*)d_in[8];
  const float* g_scale  = (const float*)d_in[9];
  const float* g_offset = (const float*)d_in[10];

  int n = in_sizes[0] / 4;
  float* out_x  = (float*)d_out;
  float* out_ld = out_x + (size_t)n * 4;
  f16* wf = (f16*)d_ws;  // 8*24*512*2 = 196608 bytes

  hipLaunchKernelGGL(prep_weights, dim3(NBLK * 24), dim3(64), 0, stream,
                     W1, b1, W2, W3, wf);
  int blocks = (n + 127) / 128;  // 128 points per 256-thread block (32/wave)
  hipLaunchKernelGGL(cinn_mfma_kernel, dim3(blocks), dim3(256), 0, stream,
                     q_feat, Hc, b2, b3, w_perm, g_scale, g_offset, wf,
                     out_x, out_ld, n);
}

// Round 6
// 301.472 us; speedup vs baseline: 1.5709x; 1.0935x over previous
//
#include <hip/hip_runtime.h>

typedef _Float16 f16;
typedef _Float16 f16x8 __attribute__((ext_vector_type(8)));
typedef float f32x4 __attribute__((ext_vector_type(4)));
typedef uint32_t u32x4 __attribute__((ext_vector_type(4)));

#define NBLK 8
#define NS 3  // independent 16-point streams per wave
#define MFMA(a, b, c) __builtin_amdgcn_mfma_f32_16x16x32_f16(a, b, c, 0, 0, 0)
#define LOG2E 1.4426950408889634f

// Consumer-side K position k -> producer-side slot feature index.
__device__ __forceinline__ int pinv(int k) {
  return 16 * (2 * (k >> 5) + ((k >> 2) & 1)) + 4 * ((k >> 3) & 3) + (k & 3);
}
__device__ __forceinline__ float hi_part(float v) { return (float)(f16)v; }
__device__ __forceinline__ float lo_part(float v) { f16 h = (f16)v; return v - (float)h; }

__device__ __forceinline__ float fast_exp2(float x) {
  float r; asm("v_exp_f32 %0, %1" : "=v"(r) : "v"(x)); return r;
}
__device__ __forceinline__ float fast_rcp(float x) {
  float r; asm("v_rcp_f32 %0, %1" : "=v"(r) : "v"(x)); return r;
}
__device__ __forceinline__ uint32_t pkrtz_u(float a, float b) {
  auto p = __builtin_amdgcn_cvt_pkrtz(a, b);
  return __builtin_bit_cast(uint32_t, p);
}
// Exact hi/lo split: hi keeps top 10 mantissa bits (exactly f16-representable).
__device__ __forceinline__ float hi_mask(float v) {
  uint32_t u = __builtin_bit_cast(uint32_t, v) & 0xFFFFE000u;
  return __builtin_bit_cast(float, u);
}

// One-time prep: fragment-layout f16 weight images + folded couple constants.
// Per block i (img 0..23, 512 f16 each):
//   img 0..3   A1[t]   (K: 0-3 W1hi, 4-7 W1lo, 8-11 W1hi, 12/13 b1 hi/lo)
//   img 4..11  A2hi[t*2+s], img 12..19 A2lo[t*2+s]
//   img 20,21  A3hi[s],     img 22,23  A3lo[s]   (W3 rows pre-scaled)
// img 24: couple constants (float, cwp): per block i, 24 floats:
//   [0..15] Wp'=Wp*diag(sc), [16..19] pb=Wp*go, [20..23] b3 pre-scaled;
//   cwp[192] = grand sum of log(scale).
__global__ void prep_weights(const float* __restrict__ W1, const float* __restrict__ b1,
                             const float* __restrict__ W2, const float* __restrict__ W3,
                             const float* __restrict__ b3, const float* __restrict__ w_perm,
                             const float* __restrict__ g_scale, const float* __restrict__ g_offset,
                             f16* __restrict__ wsp, float* __restrict__ cwp) {
  int i = blockIdx.x / 25;
  int img = blockIdx.x % 25;
  if (img == 24) {
    int tid = threadIdx.x;
    if (tid < 16) {
      int cc = tid & 3;
      float gs = g_scale[i * 4 + cc];
      float sc = 0.2f * log1pf(expf(0.5f * gs));
      cwp[i * 24 + tid] = w_perm[i * 16 + tid] * sc;
    } else if (tid < 20) {
      int r = tid - 16;
      float acc = 0.f;
      for (int cc = 0; cc < 4; ++cc)
        acc += w_perm[i * 16 + r * 4 + cc] * g_offset[i * 4 + cc];
      cwp[i * 24 + 16 + r] = acc;
    } else if (tid < 24) {
      int j = tid - 20;
      float scale = (j < 2) ? (0.2f * LOG2E) : 0.1f;
      cwp[i * 24 + 20 + j] = b3[i * 4 + j] * scale;
    } else if (tid == 24 && i == 0) {
      float acc = 0.f;
      for (int k = 0; k < 32; ++k)
        acc += logf(0.2f * log1pf(expf(0.5f * g_scale[k])));
      cwp[192] = acc;
    }
    return;
  }
  int lane = threadIdx.x;
  int c = lane & 15, g = lane >> 4;
  f16 vals[8];
#pragma unroll
  for (int e = 0; e < 8; ++e) {
    float out = 0.f;
    if (img < 4) {
      int t = img, m = 16 * t + c, k = 8 * g + e;
      if (k < 4)        out = hi_part(W1[i * 256 + m * 4 + k]);
      else if (k < 8)   out = lo_part(W1[i * 256 + m * 4 + (k - 4)]);
      else if (k < 12)  out = hi_part(W1[i * 256 + m * 4 + (k - 8)]);
      else if (k == 12) out = hi_part(b1[i * 64 + m]);
      else if (k == 13) out = lo_part(b1[i * 64 + m]);
      else out = 0.f;
    } else if (img < 20) {
      bool isLo = (img >= 12);
      int q = isLo ? (img - 12) : (img - 4);
      int t = q >> 1, s = q & 1, m = 16 * t + c;
      int k = 32 * s + 8 * g + e;
      float v = W2[i * 4096 + m * 64 + pinv(k)];
      out = isLo ? lo_part(v) : hi_part(v);
    } else {
      bool isLo = (img >= 22);
      int s = isLo ? (img - 22) : (img - 20);
      int k = 32 * s + 8 * g + e;
      float rs = (c < 2) ? (0.2f * LOG2E) : 0.1f;  // fold 0.1 and 2*log2e
      float v = (c < 4) ? W3[i * 256 + c * 64 + pinv(k)] * rs : 0.f;
      out = isLo ? lo_part(v) : hi_part(v);
    }
    vals[e] = (f16)out;
  }
  f16x8 vv = {vals[0], vals[1], vals[2], vals[3], vals[4], vals[5], vals[6], vals[7]};
  *(f16x8*)(wsp + ((size_t)i * 24 + img) * 512 + (size_t)lane * 8) = vv;
}

// Two D tiles -> relu -> exact-split f16 hi/lo fragment (one s-group).
__device__ __forceinline__ void make_b_pair(const f32x4 d0, const f32x4 d1,
                                            f16x8& bh, f16x8& bl) {
  float r[8], hf[8], lf[8];
#pragma unroll
  for (int e = 0; e < 4; ++e) {
    r[e]     = fmaxf(d0[e], 0.f);
    r[4 + e] = fmaxf(d1[e], 0.f);
  }
#pragma unroll
  for (int e = 0; e < 8; ++e) {
    hf[e] = hi_mask(r[e]);
    lf[e] = r[e] - hf[e];
  }
  u32x4 uh = {pkrtz_u(hf[0], hf[1]), pkrtz_u(hf[2], hf[3]),
              pkrtz_u(hf[4], hf[5]), pkrtz_u(hf[6], hf[7])};
  u32x4 ul = {pkrtz_u(lf[0], lf[1]), pkrtz_u(lf[2], lf[3]),
              pkrtz_u(lf[4], lf[5]), pkrtz_u(lf[6], lf[7])};
  bh = __builtin_bit_cast(f16x8, uh);
  bl = __builtin_bit_cast(f16x8, ul);
}

struct Pt {
  float x0, x1, x2, x3, ld;
  uint32_t ch_pk, cl_pk;
};

__device__ __forceinline__ f16x8 build_B1(const Pt& s, bool g0, bool g1) {
  const uint32_t ones_pk = 0x3C003C00u;  // packed f16 {1,1}
  float xh0 = hi_mask(s.x0), xh1 = hi_mask(s.x1);
  uint32_t xh_pk = pkrtz_u(xh0, xh1);
  uint32_t xl_pk = pkrtz_u(s.x0 - xh0, s.x1 - xh1);
  u32x4 B1u = {g0 ? xh_pk : (g1 ? xl_pk : 0u),
               g0 ? s.ch_pk : (g1 ? s.cl_pk : 0u),
               g0 ? xh_pk : (g1 ? ones_pk : 0u),
               g0 ? s.ch_pk : 0u};
  return __builtin_bit_cast(f16x8, B1u);
}

// d3 rows (from g=0 lanes): 0,1 = 2a*log2e ; 2,3 = t (W3 pre-scaled in prep).
__device__ __forceinline__ void couple(Pt& st, const f32x4 d3, int c,
                                       const float* __restrict__ cw) {
  float a0 = __shfl(d3[0], c, 64) + cw[20];
  float a1 = __shfl(d3[1], c, 64) + cw[21];
  float t2 = __shfl(d3[2], c, 64) + cw[22];
  float t3 = __shfl(d3[3], c, 64) + cw[23];
  float u0 = fast_exp2(a0), u1 = fast_exp2(a1);          // e^{2a}
  float s0 = fmaf(-4.f, fast_rcp(u0 + 1.f), 2.f);        // 2*tanh(a)
  float s1 = fmaf(-4.f, fast_rcp(u1 + 1.f), 2.f);
  float e0 = fast_exp2(s0 * LOG2E), e1 = fast_exp2(s1 * LOG2E);
  st.x2 = fmaf(st.x2, e0, t2);
  st.x3 = fmaf(st.x3, e1, t3);
  st.ld += s0 + s1;
  // fused actnorm+permutation: nx_r = pb[r] + sum_c Wp'[r][c]*x_c
  float nx0 = fmaf(st.x0, cw[0],  fmaf(st.x1, cw[1],  fmaf(st.x2, cw[2],  fmaf(st.x3, cw[3],  cw[16]))));
  float nx1 = fmaf(st.x0, cw[4],  fmaf(st.x1, cw[5],  fmaf(st.x2, cw[6],  fmaf(st.x3, cw[7],  cw[17]))));
  float nx2 = fmaf(st.x0, cw[8],  fmaf(st.x1, cw[9],  fmaf(st.x2, cw[10], fmaf(st.x3, cw[11], cw[18]))));
  float nx3 = fmaf(st.x0, cw[12], fmaf(st.x1, cw[13], fmaf(st.x2, cw[14], fmaf(st.x3, cw[15], cw[19]))));
  st.x0 = nx0; st.x1 = nx1; st.x2 = nx2; st.x3 = nx3;
}

// Triple-stream: each wave handles 48 points (3 independent 16-point streams).
// Weight fragments are loaded once and feed all streams' MFMAs; each stream's
// serial shfl/exp chain hides under the other streams' compute.
__global__ __launch_bounds__(256) void cinn_mfma_kernel(
    const float* __restrict__ q_feat, const float* __restrict__ Hc,
    const float* __restrict__ b2, const f16* __restrict__ wf,
    const float* __restrict__ cwp,
    float* __restrict__ out_x, float* __restrict__ out_ld, int n) {
  int lane = threadIdx.x & 63;
  int c = lane & 15, g = lane >> 4;
  bool g0 = (g == 0), g1 = (g == 1);
  int wave = (blockIdx.x * blockDim.x + threadIdx.x) >> 6;

  int pt[NS];
  Pt st[NS];
#pragma unroll
  for (int u = 0; u < NS; ++u) {
    int p = wave * (16 * NS) + u * 16 + c;
    if (p >= n) p = n - 1;  // clamped lanes compute identical results (benign)
    pt[u] = p;
    float4 xv = *reinterpret_cast<const float4*>(q_feat + (size_t)p * 4);
    st[u].x0 = xv.x; st[u].x1 = xv.y; st[u].x2 = xv.z; st[u].x3 = xv.w;
    st[u].ld = 0.f;
    float2 hv = *reinterpret_cast<const float2*>(Hc + (size_t)p * 2);
    float h0 = hi_mask(hv.x), h1 = hi_mask(hv.y);
    st[u].ch_pk = pkrtz_u(h0, h1);
    st[u].cl_pk = pkrtz_u(hv.x - h0, hv.y - h1);
  }

  const f32x4 zero4 = {0.f, 0.f, 0.f, 0.f};

#pragma unroll 1
  for (int i = 0; i < NBLK; ++i) {
    const f16* wb = wf + (size_t)i * 24 * 512 + (size_t)lane * 8;
    const float* cw = cwp + i * 24;

    f16x8 B1[NS];
#pragma unroll
    for (int u = 0; u < NS; ++u) B1[u] = build_B1(st[u], g0, g1);

    // L1 (split terms + b1 folded into K-slots)
    f16x8 b2h[NS][2], b2l[NS][2];
#pragma unroll
    for (int half = 0; half < 2; ++half) {
      f32x4 dp[NS][2];
#pragma unroll
      for (int tt = 0; tt < 2; ++tt) {
        f16x8 a = *(const f16x8*)(wb + (2 * half + tt) * 512);
#pragma unroll
        for (int u = 0; u < NS; ++u) dp[u][tt] = MFMA(a, B1[u], zero4);
      }
#pragma unroll
      for (int u = 0; u < NS; ++u)
        make_b_pair(dp[u][0], dp[u][1], b2h[u][half], b2l[u][half]);
    }

    // L2: hi*hi + lo*hi + hi*lo; b2 bias enters as MFMA C-input
    f16x8 b3h[NS][2], b3l[NS][2];
#pragma unroll
    for (int half = 0; half < 2; ++half) {
      f32x4 d2[NS][2];
#pragma unroll
      for (int tt = 0; tt < 2; ++tt) {
        int t = 2 * half + tt;
        f16x8 ah0 = *(const f16x8*)(wb + (4 + 2 * t + 0) * 512);
        f16x8 ah1 = *(const f16x8*)(wb + (4 + 2 * t + 1) * 512);
        f16x8 al0 = *(const f16x8*)(wb + (12 + 2 * t + 0) * 512);
        f16x8 al1 = *(const f16x8*)(wb + (12 + 2 * t + 1) * 512);
        const float4 bv = *reinterpret_cast<const float4*>(b2 + i * 64 + 16 * t + 4 * g);
        f32x4 cin = {bv.x, bv.y, bv.z, bv.w};
#pragma unroll
        for (int u = 0; u < NS; ++u) {
          f32x4 acc = MFMA(ah0, b2h[u][0], cin);
          acc = MFMA(ah1, b2h[u][1], acc);
          acc = MFMA(al0, b2h[u][0], acc);
          acc = MFMA(al1, b2h[u][1], acc);
          acc = MFMA(ah0, b2l[u][0], acc);
          acc = MFMA(ah1, b2l[u][1], acc);
          d2[u][tt] = acc;
        }
      }
#pragma unroll
      for (int u = 0; u < NS; ++u)
        make_b_pair(d2[u][0], d2[u][1], b3h[u][half], b3l[u][half]);
    }

    // L3 (W3 pre-scaled in prep)
    f32x4 d3[NS];
    {
      f16x8 ah0 = *(const f16x8*)(wb + 20 * 512);
      f16x8 ah1 = *(const f16x8*)(wb + 21 * 512);
      f16x8 al0 = *(const f16x8*)(wb + 22 * 512);
      f16x8 al1 = *(const f16x8*)(wb + 23 * 512);
#pragma unroll
      for (int u = 0; u < NS; ++u) {
        f32x4 acc = MFMA(ah0, b3h[u][0], zero4);
        acc = MFMA(ah1, b3h[u][1], acc);
        acc = MFMA(al0, b3h[u][0], acc);
        acc = MFMA(al1, b3h[u][1], acc);
        acc = MFMA(ah0, b3l[u][0], acc);
        acc = MFMA(ah1, b3l[u][1], acc);
        d3[u] = acc;
      }
    }

#pragma unroll
    for (int u = 0; u < NS; ++u) couple(st[u], d3[u], c, cw);
  }

  if (lane < 16) {
    float lt = cwp[192];
#pragma unroll
    for (int u = 0; u < NS; ++u) {
      *reinterpret_cast<float4*>(out_x + (size_t)pt[u] * 4) =
          make_float4(st[u].x0, st[u].x1, st[u].x2, st[u].x3);
      out_ld[pt[u]] = st[u].ld + lt;
    }
  }
}

extern "C" void kernel_launch(void* const* d_in, const int* in_sizes, int n_in,
                              void* d_out, int out_size, void* d_ws, size_t ws_size,
                              hipStream_t stream) {
  const float* q_feat   = (const float*)d_in[0];
  const float* W1       = (const float*)d_in[2];
  const float* b1       = (const float*)d_in[3];
  const float* W2       = (const float*)d_in[4];
  const float* b2       = (const float*)d_in[5];
  const float* W3       = (const float*)d_in[6];
  const float* b3       = (const float*)d_in[7];
  const float* w_perm   = (const float*)d_in[8];
  const float* g_scale  = (const float*)d_in[9];
  const float* g_offset = (const float*)d_in[10];
  const float* Hc       = (const float*)d_in[1];

  int n = in_sizes[0] / 4;
  float* out_x  = (float*)d_out;
  float* out_ld = out_x + (size_t)n * 4;
  f16* wf = (f16*)d_ws;                       // 8*24*512*2 = 196608 B
  float* cwp = (float*)((char*)d_ws + 196608); // 193 floats

  hipLaunchKernelGGL(prep_weights, dim3(NBLK * 25), dim3(64), 0, stream,
                     W1, b1, W2, W3, b3, w_perm, g_scale, g_offset, wf, cwp);
  int ppb = 256 / 64 * 16 * NS;  // points per 256-thread block = 192
  int blocks = (n + ppb - 1) / ppb;
  hipLaunchKernelGGL(cinn_mfma_kernel, dim3(blocks), dim3(256), 0, stream,
                     q_feat, Hc, b2, wf, cwp, out_x, out_ld, n);
}